// Round 6
// baseline (1058.079 us; speedup 1.0000x reference)
//
#include <hip/hip_runtime.h>
#include <math.h>

// VectorCapsules v6 — two-kernel split.
// K1 (caps_u): per-batch conv + pc einsum + squash + caps matvec -> u in d_ws
//   (SoA [b][o][n]). LDS only 42KB -> 3 blocks/CU = 6 waves/SIMD (v5 was 2).
// K2 (caps_route): per-batch 4 routing rounds reading u from global (L3-hot).
// Fallback: if ws_size < 122.5MB, launch the proven v5 monolithic kernel.

#define NTH    512
#define NWAVES 8
#define IC     6272      // 32*14*14 capsules
#define NCLS   5

// ---------------------------------------------------------------------------
// Kernel 1: compute u[b][o][n]  (SoA over classes)
// ---------------------------------------------------------------------------
__global__ __launch_bounds__(NTH, 1)
void caps_u(const float* __restrict__ inp,
            const float* __restrict__ W1,
            const float* __restrict__ b1,
            const float* __restrict__ Wp,
            const float* __restrict__ bp,
            const float* __restrict__ capsW,
            float* __restrict__ uws)
{
    extern __shared__ float lds[];
    float* s_in  = lds;              // 3481
    float* s_W1  = s_in + 3481;      // 800
    float* s_b1  = s_W1 + 800;       // 32
    float* s_xs  = s_b1 + 32;        // 6272 : xs TRANSPOSED [hw][c'], c' swizzled

    const int b    = blockIdx.x;
    const int tid  = threadIdx.x;
    const int lane = tid & 63;
    const int wv   = tid >> 6;
    const int wvs  = __builtin_amdgcn_readfirstlane(wv);   // provably uniform

    // ---------------- Phase 0: stage ----------------
    const float* inb = inp + (size_t)b * (59 * 59);
    for (int i = tid; i < 59 * 59; i += NTH) s_in[i] = inb[i];
    for (int i = tid; i < 800;     i += NTH) s_W1[i] = W1[i];
    if (tid < 32) s_b1[tid] = b1[tid];
    __syncthreads();

    // ---------------- Phase 1: conv (::2,::2 kept => stride 4) ----------
    // write transposed+swizzled: s_xs[hw*32 + 4*((c>>2)^(hw&7)) + (c&3)]
    for (int n = tid; n < IC; n += NTH) {
        const int c  = n / 196;
        const int hw = n - c * 196;
        const int h  = hw / 14;
        const int w  = hw - h * 14;
        const float* ip = s_in + (4 * h) * 59 + 4 * w;
        const float* wk = s_W1 + c * 25;
        float acc = s_b1[c];
        #pragma unroll
        for (int kh = 0; kh < 5; ++kh)
            #pragma unroll
            for (int kw = 0; kw < 5; ++kw)
                acc = fmaf(ip[kh * 59 + kw], wk[kh * 5 + kw], acc);
        const int col = 4 * ((c >> 2) ^ (hw & 7)) + (c & 3);
        s_xs[hw * 32 + col] = fmaxf(acc, 0.0f);
    }
    __syncthreads();

    // ---------------- Phase 2: pc -> squash -> u (global SoA) -------------
    // wave wv handles g = wvs + gi*8, gi 0..3; one 64-hw round at a time
    // (live set ~66 regs: x[32] + pc[14] + temps -> fits 85-reg/6-wave cap).
    const float4* xs4 = (const float4*)s_xs;
    float* ub = uws + (size_t)b * 5 * IC;

    for (int gi = 0; gi < 4; ++gi) {
        const int g = wvs + gi * 8;                 // scalar (SGPR)
        const float* wpg = Wp + g * 448;            // uniform -> s_load
        const float* bpg = bp + g * 14;             // uniform -> s_load

        #pragma unroll
        for (int r = 0; r < 4; ++r) {
            const int hw = (r < 3) ? (r * 64 + lane) : (192 + (lane & 3));
            float x[32];
            #pragma unroll
            for (int j = 0; j < 8; ++j) {
                const float4 a = xs4[hw * 8 + (j ^ (hw & 7))];
                x[4*j+0] = a.x; x[4*j+1] = a.y; x[4*j+2] = a.z; x[4*j+3] = a.w;
            }
            float pc[14];
            #pragma unroll
            for (int i = 0; i < 14; ++i) pc[i] = bpg[i];     // s_load
            #pragma unroll
            for (int i = 0; i < 14; ++i) {
                const float* wr = wpg + i * 32;              // contiguous scalars
                #pragma unroll
                for (int c = 0; c < 32; ++c)
                    pc[i] = fmaf(wr[c], x[c], pc[i]);        // v_fma v,s,v
            }
            if (r < 3 || lane < 4) {
                const int n = g * 196 + hw;
                float sq = 0.f;
                #pragma unroll
                for (int i = 0; i < 14; ++i) sq = fmaf(pc[i], pc[i], sq);
                const float scale = sqrtf(sq) / (1.0f + sq);
                float uo[NCLS] = {0.f, 0.f, 0.f, 0.f, 0.f};
                const float* cw = capsW + (size_t)n * 70;
                #pragma unroll
                for (int i = 0; i < 14; ++i) {
                    const float p = pc[i] * scale;
                    #pragma unroll
                    for (int o = 0; o < NCLS; ++o)
                        uo[o] = fmaf(p, cw[i * 5 + o], uo[o]);
                }
                #pragma unroll
                for (int o = 0; o < NCLS; ++o) ub[o * IC + n] = uo[o];  // SoA, coalesced
            }
        }
    }
}

// ---------------------------------------------------------------------------
// Kernel 2: routing (initial + 3 iters), u from global
// ---------------------------------------------------------------------------
__global__ __launch_bounds__(NTH, 1)
void caps_route(const float* __restrict__ uws,
                const float* __restrict__ broute,
                float* __restrict__ out)
{
    __shared__ float s_red[NWAVES * NCLS];
    __shared__ float s_v[8];

    const int b    = blockIdx.x;
    const int tid  = threadIdx.x;
    const int lane = tid & 63;
    const int wv   = tid >> 6;

    const float* ub = uws + (size_t)b * 5 * IC;

    float V[NCLS] = {0.f, 0.f, 0.f, 0.f, 0.f};
    for (int it = 0; it < 4; ++it) {
        float sacc[NCLS] = {0.f, 0.f, 0.f, 0.f, 0.f};
        for (int n = tid; n < IC; n += NTH) {
            const float* br = broute + (size_t)n * 5;
            float uu[NCLS], l[NCLS];
            #pragma unroll
            for (int o = 0; o < NCLS; ++o) {
                uu[o] = ub[o * IC + n];              // coalesced per-o stream
                l[o]  = fmaf(uu[o], V[o], br[o]);
            }
            const float m = fmaxf(fmaxf(fmaxf(l[0], l[1]), fmaxf(l[2], l[3])), l[4]);
            float e[NCLS], es = 0.f;
            #pragma unroll
            for (int o = 0; o < NCLS; ++o) { e[o] = __expf(l[o] - m); es += e[o]; }
            const float inv = 1.0f / es;
            #pragma unroll
            for (int o = 0; o < NCLS; ++o)
                sacc[o] = fmaf(uu[o], e[o] * inv, sacc[o]);
        }
        #pragma unroll
        for (int off = 32; off > 0; off >>= 1)
            #pragma unroll
            for (int o = 0; o < NCLS; ++o)
                sacc[o] += __shfl_down(sacc[o], off);
        if (lane == 0) {
            #pragma unroll
            for (int o = 0; o < NCLS; ++o) s_red[wv * 5 + o] = sacc[o];
        }
        __syncthreads();
        if (tid == 0) {
            #pragma unroll
            for (int o = 0; o < NCLS; ++o) {
                float s = 0.f;
                for (int w2 = 0; w2 < NWAVES; ++w2) s += s_red[w2 * 5 + o];
                s_v[o] = s * fabsf(s) / (1.0f + s * s);   // squash, OUT_DIM=1
            }
        }
        __syncthreads();
        #pragma unroll
        for (int o = 0; o < NCLS; ++o) V[o] += s_v[o];
    }

    if (tid < NCLS) out[b * NCLS + tid] = fabsf(s_v[tid]);
}

// ---------------------------------------------------------------------------
// Fallback: v5 monolithic (proven pass @687us) for small ws_size
// ---------------------------------------------------------------------------
__global__ __launch_bounds__(NTH, 1)
void caps_fused(const float* __restrict__ inp,
                const float* __restrict__ W1,
                const float* __restrict__ b1,
                const float* __restrict__ Wp,
                const float* __restrict__ bp,
                const float* __restrict__ capsW,
                const float* __restrict__ broute,
                float* __restrict__ out)
{
    extern __shared__ float lds[];
    float* s_xs  = lds;
    float* s_W1  = s_xs + 6272;
    float* s_b1  = s_W1 + 800;
    float* s_red = s_b1 + 32;
    float* s_v   = s_red + 40;
    float* s_u   = s_v + 8;
    float* s_in  = s_u;

    const int b    = blockIdx.x;
    const int tid  = threadIdx.x;
    const int lane = tid & 63;
    const int wv   = tid >> 6;
    const int wvs  = __builtin_amdgcn_readfirstlane(wv);

    const float* inb = inp + (size_t)b * (59 * 59);
    for (int i = tid; i < 59 * 59; i += NTH) s_in[i] = inb[i];
    for (int i = tid; i < 800;     i += NTH) s_W1[i] = W1[i];
    if (tid < 32) s_b1[tid] = b1[tid];
    __syncthreads();

    for (int n = tid; n < IC; n += NTH) {
        const int c  = n / 196;
        const int hw = n - c * 196;
        const int h  = hw / 14;
        const int w  = hw - h * 14;
        const float* ip = s_in + (4 * h) * 59 + 4 * w;
        const float* wk = s_W1 + c * 25;
        float acc = s_b1[c];
        #pragma unroll
        for (int kh = 0; kh < 5; ++kh)
            #pragma unroll
            for (int kw = 0; kw < 5; ++kw)
                acc = fmaf(ip[kh * 59 + kw], wk[kh * 5 + kw], acc);
        const int col = 4 * ((c >> 2) ^ (hw & 7)) + (c & 3);
        s_xs[hw * 32 + col] = fmaxf(acc, 0.0f);
    }
    __syncthreads();

    const float4* xs4 = (const float4*)s_xs;
    for (int gi = 0; gi < 4; ++gi) {
        const int g = wvs + gi * 8;
        const float* wpg = Wp + g * 448;
        const float* bpg = bp + g * 14;
        #pragma unroll
        for (int r = 0; r < 4; ++r) {
            const int hw = (r < 3) ? (r * 64 + lane) : (192 + (lane & 3));
            float x[32];
            #pragma unroll
            for (int j = 0; j < 8; ++j) {
                const float4 a = xs4[hw * 8 + (j ^ (hw & 7))];
                x[4*j+0] = a.x; x[4*j+1] = a.y; x[4*j+2] = a.z; x[4*j+3] = a.w;
            }
            float pc[14];
            #pragma unroll
            for (int i = 0; i < 14; ++i) pc[i] = bpg[i];
            #pragma unroll
            for (int i = 0; i < 14; ++i) {
                const float* wr = wpg + i * 32;
                #pragma unroll
                for (int c = 0; c < 32; ++c)
                    pc[i] = fmaf(wr[c], x[c], pc[i]);
            }
            if (r < 3 || lane < 4) {
                const int n = g * 196 + hw;
                float sq = 0.f;
                #pragma unroll
                for (int i = 0; i < 14; ++i) sq = fmaf(pc[i], pc[i], sq);
                const float scale = sqrtf(sq) / (1.0f + sq);
                float uo[NCLS] = {0.f, 0.f, 0.f, 0.f, 0.f};
                const float* cw = capsW + (size_t)n * 70;
                #pragma unroll
                for (int i = 0; i < 14; ++i) {
                    const float p = pc[i] * scale;
                    #pragma unroll
                    for (int o = 0; o < NCLS; ++o)
                        uo[o] = fmaf(p, cw[i * 5 + o], uo[o]);
                }
                #pragma unroll
                for (int o = 0; o < NCLS; ++o) s_u[n * 5 + o] = uo[o];
            }
        }
    }
    __syncthreads();

    float V[NCLS] = {0.f, 0.f, 0.f, 0.f, 0.f};
    for (int it = 0; it < 4; ++it) {
        float sacc[NCLS] = {0.f, 0.f, 0.f, 0.f, 0.f};
        for (int n = tid; n < IC; n += NTH) {
            const float* br = broute + (size_t)n * 5;
            float uu[NCLS], l[NCLS];
            #pragma unroll
            for (int o = 0; o < NCLS; ++o) {
                uu[o] = s_u[n * 5 + o];
                l[o]  = fmaf(uu[o], V[o], br[o]);
            }
            const float m = fmaxf(fmaxf(fmaxf(l[0], l[1]), fmaxf(l[2], l[3])), l[4]);
            float e[NCLS], es = 0.f;
            #pragma unroll
            for (int o = 0; o < NCLS; ++o) { e[o] = __expf(l[o] - m); es += e[o]; }
            const float inv = 1.0f / es;
            #pragma unroll
            for (int o = 0; o < NCLS; ++o)
                sacc[o] = fmaf(uu[o], e[o] * inv, sacc[o]);
        }
        #pragma unroll
        for (int off = 32; off > 0; off >>= 1)
            #pragma unroll
            for (int o = 0; o < NCLS; ++o)
                sacc[o] += __shfl_down(sacc[o], off);
        if (lane == 0) {
            #pragma unroll
            for (int o = 0; o < NCLS; ++o) s_red[wv * 5 + o] = sacc[o];
        }
        __syncthreads();
        if (tid == 0) {
            #pragma unroll
            for (int o = 0; o < NCLS; ++o) {
                float s = 0.f;
                for (int w2 = 0; w2 < NWAVES; ++w2) s += s_red[w2 * 5 + o];
                s_v[o] = s * fabsf(s) / (1.0f + s * s);
            }
        }
        __syncthreads();
        #pragma unroll
        for (int o = 0; o < NCLS; ++o) V[o] += s_v[o];
    }

    if (tid < NCLS) out[b * NCLS + tid] = fabsf(s_v[tid]);
}

extern "C" void kernel_launch(void* const* d_in, const int* in_sizes, int n_in,
                              void* d_out, int out_size, void* d_ws, size_t ws_size,
                              hipStream_t stream)
{
    const float* inp   = (const float*)d_in[0];
    // d_in[1] = r (python scalar, unused by reference)
    const float* W1    = (const float*)d_in[2];
    const float* b1    = (const float*)d_in[3];
    const float* Wp    = (const float*)d_in[4];
    const float* bp    = (const float*)d_in[5];
    const float* capsW = (const float*)d_in[6];
    const float* brt   = (const float*)d_in[7];
    float* out = (float*)d_out;

    const int B = in_sizes[0] / (59 * 59);   // 1024
    const size_t ws_need = (size_t)B * 5 * IC * sizeof(float);   // ~122.5 MB

    if (ws_size >= ws_need) {
        const size_t lds1 = (size_t)(3481 + 800 + 32 + 6272) * sizeof(float);  // 42.3KB
        caps_u<<<B, NTH, lds1, stream>>>(inp, W1, b1, Wp, bp, capsW, (float*)d_ws);
        caps_route<<<B, NTH, 0, stream>>>((const float*)d_ws, brt, out);
    } else {
        const size_t lds_bytes = (size_t)(6272 + 800 + 32 + 40 + 8 + 31360) * sizeof(float);
        (void)hipFuncSetAttribute((const void*)caps_fused,
                                  hipFuncAttributeMaxDynamicSharedMemorySize,
                                  (int)lds_bytes);
        caps_fused<<<B, NTH, lds_bytes, stream>>>(inp, W1, b1, Wp, bp, capsW, brt, out);
    }
}

// Round 7
// 623.620 us; speedup vs baseline: 1.6967x; 1.6967x over previous
//
#include <hip/hip_runtime.h>
#include <math.h>

// VectorCapsules v7 — three kernels.
// K0 (cw_t): transpose capsW [n][i*5+o] -> cwT [i*5+o][n]  (coalesced reads
//     for K1's per-capsule matvec; the old layout scattered every wave load
//     across 64 cache lines).
// K1 (caps_u2): per-batch conv + einsum + squash + capsmat -> u in d_ws.
//     256 thr, thread<->hw mapping: x[32] loaded ONCE into regs, all 32 g
//     reuse them; Wp/bp block-uniform -> s_load; cwT loads coalesced.
// K2 (caps_route): 4 routing rounds from global u (proven ~40us).
// Fallback: v5 monolithic if ws too small.

#define IC     6272      // 32*14*14 capsules
#define NCLS   5

// ---------------------------------------------------------------------------
// Kernel 0: capsW transpose -> cwT[(i*5+o)*IC + n]
// ---------------------------------------------------------------------------
__global__ __launch_bounds__(256)
void cw_t(const float* __restrict__ capsW, float* __restrict__ cwT)
{
    __shared__ float t[64 * 71];
    const int n0  = blockIdx.x * 64;
    const int tid = threadIdx.x;
    for (int f = tid; f < 64 * 70; f += 256)
        t[(f / 70) * 71 + (f % 70)] = capsW[(size_t)n0 * 70 + f];   // coalesced read
    __syncthreads();
    for (int f = tid; f < 64 * 70; f += 256) {
        const int io = f >> 6, nl = f & 63;
        cwT[(size_t)io * IC + n0 + nl] = t[nl * 71 + io];           // coalesced write
    }
}

// ---------------------------------------------------------------------------
// Kernel 1: conv + einsum + squash + capsmat -> u[b][o][n] (SoA)
// ---------------------------------------------------------------------------
__global__ __launch_bounds__(256, 3)
void caps_u2(const float* __restrict__ inp,
             const float* __restrict__ W1,
             const float* __restrict__ b1,
             const float* __restrict__ Wp,
             const float* __restrict__ bp,
             const float* __restrict__ cwT,
             float* __restrict__ uws)
{
    __shared__ float s_in[3481];
    __shared__ float s_W1[800];
    __shared__ float s_b1[32];
    __shared__ float s_xs[196 * 36];   // [hw][c], padded stride 36 (16B-aligned rows)

    const int b   = blockIdx.x;
    const int tid = threadIdx.x;

    // ---- stage ----
    const float* inb = inp + (size_t)b * 3481;
    for (int i = tid; i < 3481; i += 256) s_in[i] = inb[i];
    for (int i = tid; i < 800;  i += 256) s_W1[i] = W1[i];
    if (tid < 32) s_b1[tid] = b1[tid];
    __syncthreads();

    // ---- conv (::2,::2 kept => stride 4) ----
    for (int n = tid; n < IC; n += 256) {
        const int c  = n / 196;
        const int hw = n - c * 196;
        const int h  = hw / 14;
        const int w  = hw - h * 14;
        const float* ip = s_in + (4 * h) * 59 + 4 * w;
        const float* wk = s_W1 + c * 25;
        float acc = s_b1[c];
        #pragma unroll
        for (int kh = 0; kh < 5; ++kh)
            #pragma unroll
            for (int kw = 0; kw < 5; ++kw)
                acc = fmaf(ip[kh * 59 + kw], wk[kh * 5 + kw], acc);
        s_xs[hw * 36 + c] = fmaxf(acc, 0.0f);
    }
    __syncthreads();

    // ---- einsum + squash + capsmat, thread <-> hw ----
    const int hw   = tid;                       // active if < 196
    const int hwx  = (hw < 196) ? hw : 0;       // clamped for loads
    const bool act = (hw < 196);

    float x[32];
    {
        const float4* row = (const float4*)(s_xs + hwx * 36);
        #pragma unroll
        for (int j = 0; j < 8; ++j) {
            const float4 a = row[j];
            x[4*j+0] = a.x; x[4*j+1] = a.y; x[4*j+2] = a.z; x[4*j+3] = a.w;
        }
    }

    float* ub = uws + (size_t)b * 5 * IC;

    for (int g = 0; g < 32; ++g) {              // block-uniform loop
        const float* wpg = Wp + g * 448;        // uniform -> s_load
        const float* bpg = bp + g * 14;         // uniform -> s_load

        float pc[14];
        #pragma unroll
        for (int i = 0; i < 14; ++i) pc[i] = bpg[i];
        #pragma unroll
        for (int i = 0; i < 14; ++i) {
            const float* wr = wpg + i * 32;
            #pragma unroll
            for (int c = 0; c < 32; ++c)
                pc[i] = fmaf(wr[c], x[c], pc[i]);   // v_fma v,s,v
        }

        float sq = 0.f;
        #pragma unroll
        for (int i = 0; i < 14; ++i) sq = fmaf(pc[i], pc[i], sq);
        const float scale = sqrtf(sq) / (1.0f + sq);

        const int n = g * 196 + hwx;
        float uo[NCLS] = {0.f, 0.f, 0.f, 0.f, 0.f};
        #pragma unroll
        for (int i = 0; i < 14; ++i) {
            const float p = pc[i] * scale;
            #pragma unroll
            for (int o = 0; o < NCLS; ++o)
                uo[o] = fmaf(p, cwT[(size_t)(i * 5 + o) * IC + n], uo[o]); // coalesced
        }
        if (act) {
            #pragma unroll
            for (int o = 0; o < NCLS; ++o) ub[(size_t)o * IC + n] = uo[o]; // coalesced
        }
    }
}

// ---------------------------------------------------------------------------
// Kernel 2: routing (initial + 3 iters), u from global — unchanged from v6
// ---------------------------------------------------------------------------
#define RNTH 512
__global__ __launch_bounds__(RNTH, 1)
void caps_route(const float* __restrict__ uws,
                const float* __restrict__ broute,
                float* __restrict__ out)
{
    __shared__ float s_red[8 * NCLS];
    __shared__ float s_v[8];

    const int b    = blockIdx.x;
    const int tid  = threadIdx.x;
    const int lane = tid & 63;
    const int wv   = tid >> 6;

    const float* ub = uws + (size_t)b * 5 * IC;

    float V[NCLS] = {0.f, 0.f, 0.f, 0.f, 0.f};
    for (int it = 0; it < 4; ++it) {
        float sacc[NCLS] = {0.f, 0.f, 0.f, 0.f, 0.f};
        for (int n = tid; n < IC; n += RNTH) {
            const float* br = broute + (size_t)n * 5;
            float uu[NCLS], l[NCLS];
            #pragma unroll
            for (int o = 0; o < NCLS; ++o) {
                uu[o] = ub[(size_t)o * IC + n];
                l[o]  = fmaf(uu[o], V[o], br[o]);
            }
            const float m = fmaxf(fmaxf(fmaxf(l[0], l[1]), fmaxf(l[2], l[3])), l[4]);
            float e[NCLS], es = 0.f;
            #pragma unroll
            for (int o = 0; o < NCLS; ++o) { e[o] = __expf(l[o] - m); es += e[o]; }
            const float inv = 1.0f / es;
            #pragma unroll
            for (int o = 0; o < NCLS; ++o)
                sacc[o] = fmaf(uu[o], e[o] * inv, sacc[o]);
        }
        #pragma unroll
        for (int off = 32; off > 0; off >>= 1)
            #pragma unroll
            for (int o = 0; o < NCLS; ++o)
                sacc[o] += __shfl_down(sacc[o], off);
        if (lane == 0) {
            #pragma unroll
            for (int o = 0; o < NCLS; ++o) s_red[wv * 5 + o] = sacc[o];
        }
        __syncthreads();
        if (tid == 0) {
            #pragma unroll
            for (int o = 0; o < NCLS; ++o) {
                float s = 0.f;
                for (int w2 = 0; w2 < 8; ++w2) s += s_red[w2 * 5 + o];
                s_v[o] = s * fabsf(s) / (1.0f + s * s);   // squash, OUT_DIM=1
            }
        }
        __syncthreads();
        #pragma unroll
        for (int o = 0; o < NCLS; ++o) V[o] += s_v[o];
    }

    if (tid < NCLS) out[b * NCLS + tid] = fabsf(s_v[tid]);
}

// ---------------------------------------------------------------------------
// Fallback: v5 monolithic (proven pass @687us) for small ws_size
// ---------------------------------------------------------------------------
#define NTH 512
__global__ __launch_bounds__(NTH, 1)
void caps_fused(const float* __restrict__ inp,
                const float* __restrict__ W1,
                const float* __restrict__ b1,
                const float* __restrict__ Wp,
                const float* __restrict__ bp,
                const float* __restrict__ capsW,
                const float* __restrict__ broute,
                float* __restrict__ out)
{
    extern __shared__ float lds[];
    float* s_xs  = lds;
    float* s_W1  = s_xs + 6272;
    float* s_b1  = s_W1 + 800;
    float* s_red = s_b1 + 32;
    float* s_v   = s_red + 40;
    float* s_u   = s_v + 8;
    float* s_in  = s_u;

    const int b    = blockIdx.x;
    const int tid  = threadIdx.x;
    const int lane = tid & 63;
    const int wv   = tid >> 6;
    const int wvs  = __builtin_amdgcn_readfirstlane(wv);

    const float* inb = inp + (size_t)b * (59 * 59);
    for (int i = tid; i < 59 * 59; i += NTH) s_in[i] = inb[i];
    for (int i = tid; i < 800;     i += NTH) s_W1[i] = W1[i];
    if (tid < 32) s_b1[tid] = b1[tid];
    __syncthreads();

    for (int n = tid; n < IC; n += NTH) {
        const int c  = n / 196;
        const int hw = n - c * 196;
        const int h  = hw / 14;
        const int w  = hw - h * 14;
        const float* ip = s_in + (4 * h) * 59 + 4 * w;
        const float* wk = s_W1 + c * 25;
        float acc = s_b1[c];
        #pragma unroll
        for (int kh = 0; kh < 5; ++kh)
            #pragma unroll
            for (int kw = 0; kw < 5; ++kw)
                acc = fmaf(ip[kh * 59 + kw], wk[kh * 5 + kw], acc);
        const int col = 4 * ((c >> 2) ^ (hw & 7)) + (c & 3);
        s_xs[hw * 32 + col] = fmaxf(acc, 0.0f);
    }
    __syncthreads();

    const float4* xs4 = (const float4*)s_xs;
    for (int gi = 0; gi < 4; ++gi) {
        const int g = wvs + gi * 8;
        const float* wpg = Wp + g * 448;
        const float* bpg = bp + g * 14;
        #pragma unroll
        for (int r = 0; r < 4; ++r) {
            const int hw = (r < 3) ? (r * 64 + lane) : (192 + (lane & 3));
            float x[32];
            #pragma unroll
            for (int j = 0; j < 8; ++j) {
                const float4 a = xs4[hw * 8 + (j ^ (hw & 7))];
                x[4*j+0] = a.x; x[4*j+1] = a.y; x[4*j+2] = a.z; x[4*j+3] = a.w;
            }
            float pc[14];
            #pragma unroll
            for (int i = 0; i < 14; ++i) pc[i] = bpg[i];
            #pragma unroll
            for (int i = 0; i < 14; ++i) {
                const float* wr = wpg + i * 32;
                #pragma unroll
                for (int c = 0; c < 32; ++c)
                    pc[i] = fmaf(wr[c], x[c], pc[i]);
            }
            if (r < 3 || lane < 4) {
                const int n = g * 196 + hw;
                float sq = 0.f;
                #pragma unroll
                for (int i = 0; i < 14; ++i) sq = fmaf(pc[i], pc[i], sq);
                const float scale = sqrtf(sq) / (1.0f + sq);
                float uo[NCLS] = {0.f, 0.f, 0.f, 0.f, 0.f};
                const float* cw = capsW + (size_t)n * 70;
                #pragma unroll
                for (int i = 0; i < 14; ++i) {
                    const float p = pc[i] * scale;
                    #pragma unroll
                    for (int o = 0; o < NCLS; ++o)
                        uo[o] = fmaf(p, cw[i * 5 + o], uo[o]);
                }
                #pragma unroll
                for (int o = 0; o < NCLS; ++o) s_u[n * 5 + o] = uo[o];
            }
        }
    }
    __syncthreads();

    float V[NCLS] = {0.f, 0.f, 0.f, 0.f, 0.f};
    for (int it = 0; it < 4; ++it) {
        float sacc[NCLS] = {0.f, 0.f, 0.f, 0.f, 0.f};
        for (int n = tid; n < IC; n += NTH) {
            const float* br = broute + (size_t)n * 5;
            float uu[NCLS], l[NCLS];
            #pragma unroll
            for (int o = 0; o < NCLS; ++o) {
                uu[o] = s_u[n * 5 + o];
                l[o]  = fmaf(uu[o], V[o], br[o]);
            }
            const float m = fmaxf(fmaxf(fmaxf(l[0], l[1]), fmaxf(l[2], l[3])), l[4]);
            float e[NCLS], es = 0.f;
            #pragma unroll
            for (int o = 0; o < NCLS; ++o) { e[o] = __expf(l[o] - m); es += e[o]; }
            const float inv = 1.0f / es;
            #pragma unroll
            for (int o = 0; o < NCLS; ++o)
                sacc[o] = fmaf(uu[o], e[o] * inv, sacc[o]);
        }
        #pragma unroll
        for (int off = 32; off > 0; off >>= 1)
            #pragma unroll
            for (int o = 0; o < NCLS; ++o)
                sacc[o] += __shfl_down(sacc[o], off);
        if (lane == 0) {
            #pragma unroll
            for (int o = 0; o < NCLS; ++o) s_red[wv * 5 + o] = sacc[o];
        }
        __syncthreads();
        if (tid == 0) {
            #pragma unroll
            for (int o = 0; o < NCLS; ++o) {
                float s = 0.f;
                for (int w2 = 0; w2 < 8; ++w2) s += s_red[w2 * 5 + o];
                s_v[o] = s * fabsf(s) / (1.0f + s * s);
            }
        }
        __syncthreads();
        #pragma unroll
        for (int o = 0; o < NCLS; ++o) V[o] += s_v[o];
    }

    if (tid < NCLS) out[b * NCLS + tid] = fabsf(s_v[tid]);
}

extern "C" void kernel_launch(void* const* d_in, const int* in_sizes, int n_in,
                              void* d_out, int out_size, void* d_ws, size_t ws_size,
                              hipStream_t stream)
{
    const float* inp   = (const float*)d_in[0];
    // d_in[1] = r (python scalar, unused by reference)
    const float* W1    = (const float*)d_in[2];
    const float* b1    = (const float*)d_in[3];
    const float* Wp    = (const float*)d_in[4];
    const float* bp    = (const float*)d_in[5];
    const float* capsW = (const float*)d_in[6];
    const float* brt   = (const float*)d_in[7];
    float* out = (float*)d_out;

    const int B = in_sizes[0] / (59 * 59);   // 1024
    const size_t u_elems  = (size_t)B * 5 * IC;
    const size_t ws_need  = (u_elems + (size_t)70 * IC) * sizeof(float);  // ~124.3 MB

    if (ws_size >= ws_need) {
        float* uws = (float*)d_ws;
        float* cwT = uws + u_elems;
        cw_t     <<<IC / 64, 256, 0, stream>>>(capsW, cwT);
        caps_u2  <<<B, 256, 0, stream>>>(inp, W1, b1, Wp, bp, cwT, uws);
        caps_route<<<B, RNTH, 0, stream>>>(uws, brt, out);
    } else {
        const size_t lds_bytes = (size_t)(6272 + 800 + 32 + 40 + 8 + 31360) * sizeof(float);
        (void)hipFuncSetAttribute((const void*)caps_fused,
                                  hipFuncAttributeMaxDynamicSharedMemorySize,
                                  (int)lds_bytes);
        caps_fused<<<B, NTH, lds_bytes, stream>>>(inp, W1, b1, Wp, bp, capsW, brt, out);
    }
}